// Round 7
// baseline (245.237 us; speedup 1.0000x reference)
//
#include <hip/hip_runtime.h>
#include <hip/hip_bf16.h>

// Problem constants (fixed by setup_inputs)
#define B   8
#define T   2048
#define C   256      // channels; 64 float4
#define L   32       // query rows / label count
#define DQ  512
#define NW  2017     // T - window_size + 1
#define NK  8        // num_chunks
#define CIC 4        // window/num_chunks
#define WT  16       // w-tile per block in out kernel (16 -> 45KB LDS, 3 blocks/CU)
#define SROWS (WT + (NK-1)*CIC)   // 44 S4 rows per tile
#define LT  32       // t-rows per label block

__device__ __forceinline__ float rdlane(float v, int lane) {
  return __int_as_float(__builtin_amdgcn_readlane(__float_as_int(v), lane));
}

// ---------------- Kernel 1: enc1/enc2 = query @ W{1,2} + b{1,2} ----------------
// grid (8 lgroups, 8 b), block 256 (=c). q broadcast via v_readlane from VGPRs:
// each wave preloads its 4 q-rows (8KB) into 32 VGPRs coalesced, then extracts
// wave-uniform scalars with readlane (VALU pipe). No LDS (R5: 16 waves x 512
// uniform ds_read_b32 serialized on one LDS pipe ~= 20us), no uniform-global-
// load gamble (R6: compiler didn't scalarize -> 36us latency-bound).
__global__ __launch_bounds__(256) void enc_kernel(
    const float* __restrict__ query, const float* __restrict__ W1,
    const float* __restrict__ b1, const float* __restrict__ W2,
    const float* __restrict__ b2, float* __restrict__ enc1,
    float* __restrict__ enc2) {
  const int b = blockIdx.y, lg = blockIdx.x;   // 4 l per block
  const int c = threadIdx.x;                   // 0..255 output channel
  const int lane = c & 63;

  // qreg[j][r] holds q[lg*4+j][ 4*(r*64+lane) .. +3 ]
  const float4* q4 = (const float4*)(query + ((size_t)b * L + lg * 4) * DQ);
  float4 qreg[4][2];
#pragma unroll
  for (int j = 0; j < 4; ++j)
#pragma unroll
    for (int r = 0; r < 2; ++r)
      qreg[j][r] = q4[j * (DQ / 4) + r * 64 + lane];

  float a1[4] = {0.f, 0.f, 0.f, 0.f};
  float a2[4] = {0.f, 0.f, 0.f, 0.f};
#pragma unroll 2
  for (int g = 0; g < DQ / 4; ++g) {     // float4-groups of d
    const int src = g & 63;              // wave-uniform source lane
    const int reg = g >> 6;
    float qv[4][4];
#pragma unroll
    for (int j = 0; j < 4; ++j) {
      qv[j][0] = rdlane(qreg[j][reg].x, src);
      qv[j][1] = rdlane(qreg[j][reg].y, src);
      qv[j][2] = rdlane(qreg[j][reg].z, src);
      qv[j][3] = rdlane(qreg[j][reg].w, src);
    }
#pragma unroll
    for (int dd = 0; dd < 4; ++dd) {
      const int d = 4 * g + dd;
      const float w1 = W1[d * C + c];
      const float w2 = W2[d * C + c];
#pragma unroll
      for (int j = 0; j < 4; ++j) {
        a1[j] = fmaf(qv[j][dd], w1, a1[j]);
        a2[j] = fmaf(qv[j][dd], w2, a2[j]);
      }
    }
  }
  const float bb1 = b1[c], bb2 = b2[c];
#pragma unroll
  for (int j = 0; j < 4; ++j) {
    const size_t off = ((size_t)b * L + lg * 4 + j) * C + c;
    enc1[off] = a1[j] + bb1;
    enc2[off] = a2[j] + bb2;
  }
}

// ---------------- Kernel 2: clip_labels = argmax_l (vis . enc1) ----------------
// grid (T/32=64, 8 b), block 256. Stage 32 rows coalesced -> LDS; sim with
// enc1 fragments in registers. Per-wave LDS reads are 2-address broadcasts
// (2-way = free, m136). LDS ~51 KB -> 3 blocks/CU.
__global__ __launch_bounds__(256) void label_kernel(
    const float* __restrict__ vis, const float* __restrict__ enc1,
    int* __restrict__ labels) {
  const int b = blockIdx.y;
  const int t0 = blockIdx.x * LT;
  const int tid = threadIdx.x;
  const int l = tid & 31;     // label row
  const int part = tid >> 5;  // 8-way channel split (32 ch each)
  __shared__ float4 raw[LT * (C / 4)];               // 32 KB
  __shared__ alignas(16) float pacc[4][LT][36];      // 18.4 KB

  float4 ef[8];
  {
    const float4* e1p = (const float4*)(enc1 + ((size_t)b * L + l) * C) + part * 8;
#pragma unroll
    for (int j = 0; j < 8; ++j) ef[j] = e1p[j];   // L2-hot
  }
  const float4* vb = (const float4*)(vis + (size_t)b * T * C);
  for (int i = tid; i < LT * (C / 4); i += 256)
    raw[i] = vb[(size_t)(t0 + (i >> 6)) * (C / 4) + (i & 63)];
  __syncthreads();

  for (int t = 0; t < LT; ++t) {
    const float4* vr = &raw[t * (C / 4) + part * 8];
    float a = 0.f;
#pragma unroll
    for (int j = 0; j < 8; ++j) {
      const float4 v = vr[j];
      a = fmaf(v.x, ef[j].x, fmaf(v.y, ef[j].y, fmaf(v.z, ef[j].z, fmaf(v.w, ef[j].w, a))));
    }
    a += __shfl_down(a, 32);                    // part pair sum (deterministic)
    if (!(tid & 32)) pacc[tid >> 6][t][l] = a;  // banks (4t+l)%32 distinct: free
  }
  __syncthreads();

  // argmax over l, first max wins (matches jnp.argmax); sum order == R5
  if (tid < LT) {
    float4 s4[8];
#pragma unroll
    for (int j = 0; j < 8; ++j) s4[j] = make_float4(0.f, 0.f, 0.f, 0.f);
#pragma unroll
    for (int p = 0; p < 4; ++p) {
      const float4* pp = (const float4*)pacc[p][tid];
#pragma unroll
      for (int j = 0; j < 8; ++j) {
        s4[j].x += pp[j].x; s4[j].y += pp[j].y;
        s4[j].z += pp[j].z; s4[j].w += pp[j].w;
      }
    }
    float bv = -INFINITY;
    int bi = 0;
#pragma unroll
    for (int j = 0; j < 8; ++j) {
      if (s4[j].x > bv) { bv = s4[j].x; bi = 4 * j; }
      if (s4[j].y > bv) { bv = s4[j].y; bi = 4 * j + 1; }
      if (s4[j].z > bv) { bv = s4[j].z; bi = 4 * j + 2; }
      if (s4[j].w > bv) { bv = s4[j].w; bi = 4 * j + 3; }
    }
    labels[(size_t)b * T + t0 + tid] = bi;
  }
}

// ---------------- Kernel 3: majority vote + S4 means + modulated output ----------------
// grid (ceil(NW/16)=127, 8 b), block 256. LDS ~45 KB -> 3 blocks/CU, 1016
// blocks -> ~4/CU: store phases overlap across resident blocks.
__global__ __launch_bounds__(256) void out_kernel(
    const float* __restrict__ vis, const float* __restrict__ enc2,
    const int* __restrict__ labels, float* __restrict__ out) {
  const int b = blockIdx.y;
  const int w0 = blockIdx.x * WT;
  const int tid = threadIdx.x;
  const int lane = tid & 63;
  const int wv = tid >> 6;              // wave id, wave-uniform
  __shared__ float4 S4[SROWS * (C / 4)];  // 44 KB, pre-scaled by 0.25
  __shared__ int slbl[SROWS];

  // Prefetch this thread's 4 vote labels (in flight alongside raw loads)
  int l0 = 0, l1 = 0, l2 = 0, l3 = 0;
  if (tid < SROWS) {
    const int* lb = labels + (size_t)b * T;
    const int t = w0 + tid;
#define LCL(tt) lb[(tt) > (T - 1) ? (T - 1) : (tt)]
    l0 = LCL(t); l1 = LCL(t + 1); l2 = LCL(t + 2); l3 = LCL(t + 3);
#undef LCL
  }

  // Phase 1: 14 independent raw-row loads per wave (one vmcnt drain)
  const float4* vb = (const float4*)(vis + (size_t)b * T * C);
  float4 r[SROWS / 4 + 3];
  {
    const int s0 = wv * (SROWS / 4);
#pragma unroll
    for (int j = 0; j < SROWS / 4 + 3; ++j) {
      int t = w0 + s0 + j;
      t = t > (T - 1) ? (T - 1) : t;    // clamp; clamped rows never used
      r[j] = vb[(size_t)t * (C / 4) + lane];
    }
  }

  // Phase 2: majority vote (tie -> smallest label == argmax of one-hot counts)
  if (tid < SROWS) {
    const int c0 = 1 + (l0 == l1) + (l0 == l2) + (l0 == l3);
    const int c1 = 1 + (l1 == l0) + (l1 == l2) + (l1 == l3);
    const int c2 = 1 + (l2 == l0) + (l2 == l1) + (l2 == l3);
    const int c3 = 1 + (l3 == l0) + (l3 == l1) + (l3 == l2);
    int best = l0, bc = c0;
    if (c1 > bc || (c1 == bc && l1 < best)) { best = l1; bc = c1; }
    if (c2 > bc || (c2 == bc && l2 < best)) { best = l2; bc = c2; }
    if (c3 > bc || (c3 == bc && l3 < best)) { best = l3; bc = c3; }
    slbl[tid] = best;
  }

  // Phase 3: S4[s] = mean4(raw rows s..s+3), 11 rows per wave
  {
    const int s0 = wv * (SROWS / 4);
#pragma unroll
    for (int s = 0; s < SROWS / 4; ++s) {
      float4 o;
      o.x = (r[s].x + r[s + 1].x + r[s + 2].x + r[s + 3].x) * 0.25f;
      o.y = (r[s].y + r[s + 1].y + r[s + 2].y + r[s + 3].y) * 0.25f;
      o.z = (r[s].z + r[s + 1].z + r[s + 2].z + r[s + 3].z) * 0.25f;
      o.w = (r[s].w + r[s + 1].w + r[s + 2].w + r[s + 3].w) * 0.25f;
      S4[(s0 + s) * (C / 4) + lane] = o;
    }
  }
  __syncthreads();

  // Phase 4: output. wave wv owns k in {wv, wv+4}; fully coalesced 1KB stores
  const float4* e2b = (const float4*)(enc2 + (size_t)b * L * C);
  float4* outp = (float4*)out;
  const int wlim = (NW - w0) < WT ? (NW - w0) : WT;
#pragma unroll
  for (int kk = 0; kk < 2; ++kk) {
    const int k = wv + kk * 4;
#pragma unroll 4
    for (int w = 0; w < wlim; ++w) {
      const int s = w + CIC * k;
      const int lb = slbl[s];                       // LDS broadcast
      const float4 e = e2b[lb * (C / 4) + lane];    // L1/L2-hot (32 KB set)
      const float4 sv = S4[s * (C / 4) + lane];
      float4 o;
      o.x = e.x * sv.x; o.y = e.y * sv.y; o.z = e.z * sv.z; o.w = e.w * sv.w;
      outp[(((size_t)b * NW + w0 + w) * NK + k) * (C / 4) + lane] = o;
    }
  }
}

extern "C" void kernel_launch(void* const* d_in, const int* in_sizes, int n_in,
                              void* d_out, int out_size, void* d_ws, size_t ws_size,
                              hipStream_t stream) {
  const float* vis   = (const float*)d_in[0];
  const float* query = (const float*)d_in[1];
  const float* W1    = (const float*)d_in[2];
  const float* b1    = (const float*)d_in[3];
  const float* W2    = (const float*)d_in[4];
  const float* b2    = (const float*)d_in[5];
  float* out = (float*)d_out;

  // Workspace: enc1 (64K f), enc2 (64K f), labels (16K int) = 576 KB
  float* enc1 = (float*)d_ws;
  float* enc2 = enc1 + (size_t)B * L * C;
  int* labels = (int*)(enc2 + (size_t)B * L * C);

  enc_kernel<<<dim3(L / 4, B), 256, 0, stream>>>(query, W1, b1, W2, b2, enc1, enc2);
  label_kernel<<<dim3(T / LT, B), 256, 0, stream>>>(vis, enc1, labels);
  out_kernel<<<dim3((NW + WT - 1) / WT, B), 256, 0, stream>>>(vis, enc2, labels, out);
}

// Round 9
// 203.758 us; speedup vs baseline: 1.2036x; 1.2036x over previous
//
#include <hip/hip_runtime.h>
#include <hip/hip_bf16.h>

// Problem constants (fixed by setup_inputs)
#define B   8
#define T   2048
#define C   256      // channels; 64 float4
#define L   32       // query rows / label count
#define DQ  512
#define NW  2017     // T - window_size + 1
#define NK  8        // num_chunks
#define CIC 4        // window/num_chunks
#define WT  32       // w-tile per block in out kernel (R5 best config)
#define SROWS (WT + (NK-1)*CIC)   // 60 S4 rows per tile
#define LT  32       // t-rows per label block
#define DS  4        // d-split factor for enc
#define DSL (DQ / DS)             // 128 d per slice
#define PCHUNK (2 * B * L * C)    // 131072 floats per ds-slice of partials

// ------------- Kernel 1a: enc partials over a d-slice -------------
// grid (8 lg, 8 b, 4 ds) = 256 blocks -> 1/CU. Per-CU LDS-broadcast cost:
// 4 waves x 128 ds_read_b128 x 12cyc ~= 6k cyc ~= 2.6us (vs R5's 16-wave
// b32 version ~47k cyc ~= 20us on one CU's LDS pipe).
__global__ __launch_bounds__(256) void enc_partial(
    const float* __restrict__ query, const float* __restrict__ W1,
    const float* __restrict__ W2, float* __restrict__ P) {
  const int lg = blockIdx.x, b = blockIdx.y, ds = blockIdx.z;
  const int c = threadIdx.x;                 // 0..255 output channel
  __shared__ float4 qs4[4][DSL / 4];         // [j][g], 2 KB

  // Stage q slice: 4 rows x 128 floats, coalesced float4
  if (c < 4 * (DSL / 4)) {
    const int j = c >> 5, g = c & 31;
    qs4[j][g] = ((const float4*)(query + ((size_t)b * L + lg * 4 + j) * DQ + ds * DSL))[g];
  }
  __syncthreads();

  float a1[4] = {0.f, 0.f, 0.f, 0.f};
  float a2[4] = {0.f, 0.f, 0.f, 0.f};
#pragma unroll 4
  for (int g = 0; g < DSL / 4; ++g) {
    const float4 q0 = qs4[0][g], q1 = qs4[1][g], q2 = qs4[2][g], q3 = qs4[3][g];
    const float* wp1 = W1 + (size_t)(ds * DSL + 4 * g) * C + c;
    const float* wp2 = W2 + (size_t)(ds * DSL + 4 * g) * C + c;
    const float w10 = wp1[0], w11 = wp1[C], w12 = wp1[2 * C], w13 = wp1[3 * C];
    const float w20 = wp2[0], w21 = wp2[C], w22 = wp2[2 * C], w23 = wp2[3 * C];
    a1[0] = fmaf(q0.x, w10, fmaf(q0.y, w11, fmaf(q0.z, w12, fmaf(q0.w, w13, a1[0]))));
    a1[1] = fmaf(q1.x, w10, fmaf(q1.y, w11, fmaf(q1.z, w12, fmaf(q1.w, w13, a1[1]))));
    a1[2] = fmaf(q2.x, w10, fmaf(q2.y, w11, fmaf(q2.z, w12, fmaf(q2.w, w13, a1[2]))));
    a1[3] = fmaf(q3.x, w10, fmaf(q3.y, w11, fmaf(q3.z, w12, fmaf(q3.w, w13, a1[3]))));
    a2[0] = fmaf(q0.x, w20, fmaf(q0.y, w21, fmaf(q0.z, w22, fmaf(q0.w, w23, a2[0]))));
    a2[1] = fmaf(q1.x, w20, fmaf(q1.y, w21, fmaf(q1.z, w22, fmaf(q1.w, w23, a2[1]))));
    a2[2] = fmaf(q2.x, w20, fmaf(q2.y, w21, fmaf(q2.z, w22, fmaf(q2.w, w23, a2[2]))));
    a2[3] = fmaf(q3.x, w20, fmaf(q3.y, w21, fmaf(q3.z, w22, fmaf(q3.w, w23, a2[3]))));
  }

  // P row = ds*2*B*L + e*B*L + (b*L + lg*4 + j), row size C
#pragma unroll
  for (int j = 0; j < 4; ++j) {
    const size_t base = ((((size_t)ds * 2 + 0) * B + b) * 8 + lg) * 4 + j;
    P[base * C + c] = a1[j];
    P[(base + (size_t)B * 8 * 4) * C + c] = a2[j];   // e=1 offset (B*L rows)
  }
}

// ------------- Kernel 1b: reduce 4 d-slices + bias -> enc1/enc2 -------------
// Deterministic fixed-order sum. R8 BUGFIX: k<8 (was k<4 -> enc2 never
// written, stayed poison -> absmax 7.22 == max|ref|). 64*256*8 = 131072 ✓.
__global__ __launch_bounds__(256) void enc_reduce(
    const float* __restrict__ P, const float* __restrict__ b1,
    const float* __restrict__ b2, float* __restrict__ enc1,
    float* __restrict__ enc2) {
  const int tid = threadIdx.x;
#pragma unroll
  for (int k = 0; k < 8; ++k) {   // 64 blocks x 256 x 8 = 131072 = 2*B*L*C
    const int idx = (blockIdx.x * 8 + k) * 256 + tid;   // [e][b][lg][j][c]
    const float v = P[idx] + P[idx + PCHUNK] + P[idx + 2 * PCHUNK] + P[idx + 3 * PCHUNK];
    const int e = idx >> 16;          // 65536 = B*L*C per e
    const int r = idx & 65535;        // == (b*L + lg*4 + j)*C + c
    const int cc = idx & 255;
    if (e == 0) enc1[r] = v + b1[cc];
    else        enc2[r] = v + b2[cc];
  }
}

// ---------------- Kernel 2: clip_labels = argmax_l (vis . enc1) ----------------
// (byte-identical to R5 best)
__global__ __launch_bounds__(256) void label_kernel(
    const float* __restrict__ vis, const float* __restrict__ enc1,
    int* __restrict__ labels) {
  const int b = blockIdx.y;
  const int t0 = blockIdx.x * LT;
  const int tid = threadIdx.x;
  const int l = tid & 31;     // label row
  const int part = tid >> 5;  // 8-way channel split (32 ch each)
  __shared__ float4 raw[LT * (C / 4)];               // 32 KB
  __shared__ alignas(16) float pacc[4][LT][36];      // 18.4 KB

  float4 ef[8];
  {
    const float4* e1p = (const float4*)(enc1 + ((size_t)b * L + l) * C) + part * 8;
#pragma unroll
    for (int j = 0; j < 8; ++j) ef[j] = e1p[j];   // L2-hot
  }
  const float4* vb = (const float4*)(vis + (size_t)b * T * C);
  for (int i = tid; i < LT * (C / 4); i += 256)
    raw[i] = vb[(size_t)(t0 + (i >> 6)) * (C / 4) + (i & 63)];
  __syncthreads();

  for (int t = 0; t < LT; ++t) {
    const float4* vr = &raw[t * (C / 4) + part * 8];
    float a = 0.f;
#pragma unroll
    for (int j = 0; j < 8; ++j) {
      const float4 v = vr[j];
      a = fmaf(v.x, ef[j].x, fmaf(v.y, ef[j].y, fmaf(v.z, ef[j].z, fmaf(v.w, ef[j].w, a))));
    }
    a += __shfl_down(a, 32);                    // part pair sum (deterministic)
    if (!(tid & 32)) pacc[tid >> 6][t][l] = a;  // banks (4t+l)%32 distinct: free
  }
  __syncthreads();

  if (tid < LT) {
    float4 s4[8];
#pragma unroll
    for (int j = 0; j < 8; ++j) s4[j] = make_float4(0.f, 0.f, 0.f, 0.f);
#pragma unroll
    for (int p = 0; p < 4; ++p) {
      const float4* pp = (const float4*)pacc[p][tid];
#pragma unroll
      for (int j = 0; j < 8; ++j) {
        s4[j].x += pp[j].x; s4[j].y += pp[j].y;
        s4[j].z += pp[j].z; s4[j].w += pp[j].w;
      }
    }
    float bv = -INFINITY;
    int bi = 0;
#pragma unroll
    for (int j = 0; j < 8; ++j) {
      if (s4[j].x > bv) { bv = s4[j].x; bi = 4 * j; }
      if (s4[j].y > bv) { bv = s4[j].y; bi = 4 * j + 1; }
      if (s4[j].z > bv) { bv = s4[j].z; bi = 4 * j + 2; }
      if (s4[j].w > bv) { bv = s4[j].w; bi = 4 * j + 3; }
    }
    labels[(size_t)b * T + t0 + tid] = bi;
  }
}

// ---------------- Kernel 3: majority vote + S4 means + modulated output ----------------
// (byte-identical to R5 best: WT=32, 60 KB LDS, 2 blocks/CU)
__global__ __launch_bounds__(256) void out_kernel(
    const float* __restrict__ vis, const float* __restrict__ enc2,
    const int* __restrict__ labels, float* __restrict__ out) {
  const int b = blockIdx.y;
  const int w0 = blockIdx.x * WT;
  const int tid = threadIdx.x;
  const int lane = tid & 63;
  const int wv = tid >> 6;              // wave id, wave-uniform
  __shared__ float4 S4[SROWS * (C / 4)];  // 60 KB, pre-scaled by 0.25
  __shared__ int slbl[SROWS];

  int l0 = 0, l1 = 0, l2 = 0, l3 = 0;
  if (tid < SROWS) {
    const int* lb = labels + (size_t)b * T;
    const int t = w0 + tid;
#define LCL(tt) lb[(tt) > (T - 1) ? (T - 1) : (tt)]
    l0 = LCL(t); l1 = LCL(t + 1); l2 = LCL(t + 2); l3 = LCL(t + 3);
#undef LCL
  }

  const float4* vb = (const float4*)(vis + (size_t)b * T * C);
  float4 r[18];
  {
    const int s0 = wv * (SROWS / 4);
#pragma unroll
    for (int j = 0; j < 18; ++j) {
      int t = w0 + s0 + j;
      t = t > (T - 1) ? (T - 1) : t;    // clamp; clamped rows never used
      r[j] = vb[(size_t)t * (C / 4) + lane];
    }
  }

  if (tid < SROWS) {
    const int c0 = 1 + (l0 == l1) + (l0 == l2) + (l0 == l3);
    const int c1 = 1 + (l1 == l0) + (l1 == l2) + (l1 == l3);
    const int c2 = 1 + (l2 == l0) + (l2 == l1) + (l2 == l3);
    const int c3 = 1 + (l3 == l0) + (l3 == l1) + (l3 == l2);
    int best = l0, bc = c0;
    if (c1 > bc || (c1 == bc && l1 < best)) { best = l1; bc = c1; }
    if (c2 > bc || (c2 == bc && l2 < best)) { best = l2; bc = c2; }
    if (c3 > bc || (c3 == bc && l3 < best)) { best = l3; bc = c3; }
    slbl[tid] = best;
  }

  {
    const int s0 = wv * (SROWS / 4);
#pragma unroll
    for (int s = 0; s < SROWS / 4; ++s) {
      float4 o;
      o.x = (r[s].x + r[s + 1].x + r[s + 2].x + r[s + 3].x) * 0.25f;
      o.y = (r[s].y + r[s + 1].y + r[s + 2].y + r[s + 3].y) * 0.25f;
      o.z = (r[s].z + r[s + 1].z + r[s + 2].z + r[s + 3].z) * 0.25f;
      o.w = (r[s].w + r[s + 1].w + r[s + 2].w + r[s + 3].w) * 0.25f;
      S4[(s0 + s) * (C / 4) + lane] = o;
    }
  }
  __syncthreads();

  const float4* e2b = (const float4*)(enc2 + (size_t)b * L * C);
  float4* outp = (float4*)out;
  const int wlim = (NW - w0) < WT ? (NW - w0) : WT;
#pragma unroll
  for (int kk = 0; kk < 2; ++kk) {
    const int k = wv + kk * 4;
#pragma unroll 4
    for (int w = 0; w < wlim; ++w) {
      const int s = w + CIC * k;
      const int lb = slbl[s];                       // LDS broadcast
      const float4 e = e2b[lb * (C / 4) + lane];    // L1/L2-hot (32 KB set)
      const float4 sv = S4[s * (C / 4) + lane];
      float4 o;
      o.x = e.x * sv.x; o.y = e.y * sv.y; o.z = e.z * sv.z; o.w = e.w * sv.w;
      outp[(((size_t)b * NW + w0 + w) * NK + k) * (C / 4) + lane] = o;
    }
  }
}

extern "C" void kernel_launch(void* const* d_in, const int* in_sizes, int n_in,
                              void* d_out, int out_size, void* d_ws, size_t ws_size,
                              hipStream_t stream) {
  const float* vis   = (const float*)d_in[0];
  const float* query = (const float*)d_in[1];
  const float* W1    = (const float*)d_in[2];
  const float* b1    = (const float*)d_in[3];
  const float* W2    = (const float*)d_in[4];
  const float* b2    = (const float*)d_in[5];
  float* out = (float*)d_out;

  // Workspace: enc1 (64K f), enc2 (64K f), labels (16K i), P (512K f) ~ 2.6 MB
  float* enc1 = (float*)d_ws;
  float* enc2 = enc1 + (size_t)B * L * C;
  int* labels = (int*)(enc2 + (size_t)B * L * C);
  float* P = (float*)(labels + (size_t)B * T);

  enc_partial<<<dim3(8, B, DS), 256, 0, stream>>>(query, W1, W2, P);
  enc_reduce<<<64, 256, 0, stream>>>(P, b1, b2, enc1, enc2);
  label_kernel<<<dim3(T / LT, B), 256, 0, stream>>>(vis, enc1, labels);
  out_kernel<<<dim3((NW + WT - 1) / WT, B), 256, 0, stream>>>(vis, enc2, labels, out);
}

// Round 11
// 185.398 us; speedup vs baseline: 1.3228x; 1.0990x over previous
//
#include <hip/hip_runtime.h>
#include <hip/hip_bf16.h>

// Problem constants (fixed by setup_inputs)
#define B   8
#define T   2048
#define C   256      // channels; 64 float4
#define L   32       // query rows / label count
#define DQ  512
#define NW  2017     // T - window_size + 1
#define NK  8        // num_chunks
#define CIC 4        // window/num_chunks
#define WT  32       // w-tile per block in out kernel (R5/R9 best config)
#define SROWS (WT + (NK-1)*CIC)   // 60 S4 rows per tile
#define LT  32       // t-rows per label block

typedef float nfloat4 __attribute__((ext_vector_type(4)));  // native vec for nt-store

// ---------------- Kernel 1: enc1/enc2 = query @ W{1,2} + b{1,2} ----------------
// Single kernel, c-split (no global reduction needed, unlike R9's d-split+reduce).
// grid (8 lg, 8 b, 4 cs) = 256 blocks -> 1/CU. block = 64 c x 4 d-quarters.
// q staged once (8 KB), read as wave-uniform b128 broadcasts: 128 issues/wave
// x 12 cyc x 4 waves ~= 6k cyc/CU ~= 2.5us. Quarter-reduce via 8 KB LDS.
// Summation order identical to R9 (quarters 0->3, sequential d within, bias last).
__global__ __launch_bounds__(256) void enc_kernel(
    const float* __restrict__ query, const float* __restrict__ W1,
    const float* __restrict__ b1, const float* __restrict__ W2,
    const float* __restrict__ b2, float* __restrict__ enc1,
    float* __restrict__ enc2) {
  const int lg = blockIdx.x, b = blockIdx.y, cs = blockIdx.z;
  const int tid = threadIdx.x;
  const int tx = tid & 63;    // channel within 64-slice
  const int dq = tid >> 6;    // d-quarter (wave-uniform)
  const int c = cs * 64 + tx;
  __shared__ float4 qs4[4][DQ / 4];        // [j][g] 8 KB
  __shared__ float red[2][4][4][64];       // [e][dq][j][tx] 8 KB

  // Stage q: 4 rows x 128 float4, coalesced
  const float4* q4 = (const float4*)(query + ((size_t)b * L + lg * 4) * DQ);
  for (int i = tid; i < 4 * (DQ / 4); i += 256) {
    const int j = i >> 7, g = i & 127;
    qs4[j][g] = q4[j * (DQ / 4) + g];
  }
  __syncthreads();

  float a1[4] = {0.f, 0.f, 0.f, 0.f};
  float a2[4] = {0.f, 0.f, 0.f, 0.f};
  const int g0 = dq * 32;
#pragma unroll 4
  for (int gg = 0; gg < 32; ++gg) {
    const int g = g0 + gg;
    const float4 q0 = qs4[0][g], q1 = qs4[1][g], q2 = qs4[2][g], q3 = qs4[3][g];
    const float* wp1 = W1 + (size_t)(4 * g) * C + c;
    const float* wp2 = W2 + (size_t)(4 * g) * C + c;
    const float w10 = wp1[0], w11 = wp1[C], w12 = wp1[2 * C], w13 = wp1[3 * C];
    const float w20 = wp2[0], w21 = wp2[C], w22 = wp2[2 * C], w23 = wp2[3 * C];
    a1[0] = fmaf(q0.x, w10, fmaf(q0.y, w11, fmaf(q0.z, w12, fmaf(q0.w, w13, a1[0]))));
    a1[1] = fmaf(q1.x, w10, fmaf(q1.y, w11, fmaf(q1.z, w12, fmaf(q1.w, w13, a1[1]))));
    a1[2] = fmaf(q2.x, w10, fmaf(q2.y, w11, fmaf(q2.z, w12, fmaf(q2.w, w13, a1[2]))));
    a1[3] = fmaf(q3.x, w10, fmaf(q3.y, w11, fmaf(q3.z, w12, fmaf(q3.w, w13, a1[3]))));
    a2[0] = fmaf(q0.x, w20, fmaf(q0.y, w21, fmaf(q0.z, w22, fmaf(q0.w, w23, a2[0]))));
    a2[1] = fmaf(q1.x, w20, fmaf(q1.y, w21, fmaf(q1.z, w22, fmaf(q1.w, w23, a2[1]))));
    a2[2] = fmaf(q2.x, w20, fmaf(q2.y, w21, fmaf(q2.z, w22, fmaf(q2.w, w23, a2[2]))));
    a2[3] = fmaf(q3.x, w20, fmaf(q3.y, w21, fmaf(q3.z, w22, fmaf(q3.w, w23, a2[3]))));
  }
#pragma unroll
  for (int j = 0; j < 4; ++j) {
    red[0][dq][j][tx] = a1[j];
    red[1][dq][j][tx] = a2[j];
  }
  __syncthreads();

  // 512 outputs (2 e x 4 j x 64 tx); 256 threads -> 2 each. Fixed-order sum.
  for (int o = tid; o < 512; o += 256) {
    const int e = o >> 8, j = (o >> 6) & 3, t = o & 63;
    const float v = red[e][0][j][t] + red[e][1][j][t] +
                    red[e][2][j][t] + red[e][3][j][t];
    const int cc = cs * 64 + t;
    const size_t off = ((size_t)b * L + lg * 4 + j) * C + cc;
    if (e == 0) enc1[off] = v + b1[cc];
    else        enc2[off] = v + b2[cc];
  }
}

// ---------------- Kernel 2: clip_labels = argmax_l (vis . enc1) ----------------
// (byte-identical to R9)
__global__ __launch_bounds__(256) void label_kernel(
    const float* __restrict__ vis, const float* __restrict__ enc1,
    int* __restrict__ labels) {
  const int b = blockIdx.y;
  const int t0 = blockIdx.x * LT;
  const int tid = threadIdx.x;
  const int l = tid & 31;     // label row
  const int part = tid >> 5;  // 8-way channel split (32 ch each)
  __shared__ float4 raw[LT * (C / 4)];               // 32 KB
  __shared__ alignas(16) float pacc[4][LT][36];      // 18.4 KB

  float4 ef[8];
  {
    const float4* e1p = (const float4*)(enc1 + ((size_t)b * L + l) * C) + part * 8;
#pragma unroll
    for (int j = 0; j < 8; ++j) ef[j] = e1p[j];   // L2-hot
  }
  const float4* vb = (const float4*)(vis + (size_t)b * T * C);
  for (int i = tid; i < LT * (C / 4); i += 256)
    raw[i] = vb[(size_t)(t0 + (i >> 6)) * (C / 4) + (i & 63)];
  __syncthreads();

  for (int t = 0; t < LT; ++t) {
    const float4* vr = &raw[t * (C / 4) + part * 8];
    float a = 0.f;
#pragma unroll
    for (int j = 0; j < 8; ++j) {
      const float4 v = vr[j];
      a = fmaf(v.x, ef[j].x, fmaf(v.y, ef[j].y, fmaf(v.z, ef[j].z, fmaf(v.w, ef[j].w, a))));
    }
    a += __shfl_down(a, 32);                    // part pair sum (deterministic)
    if (!(tid & 32)) pacc[tid >> 6][t][l] = a;  // banks (4t+l)%32 distinct: free
  }
  __syncthreads();

  if (tid < LT) {
    float4 s4[8];
#pragma unroll
    for (int j = 0; j < 8; ++j) s4[j] = make_float4(0.f, 0.f, 0.f, 0.f);
#pragma unroll
    for (int p = 0; p < 4; ++p) {
      const float4* pp = (const float4*)pacc[p][tid];
#pragma unroll
      for (int j = 0; j < 8; ++j) {
        s4[j].x += pp[j].x; s4[j].y += pp[j].y;
        s4[j].z += pp[j].z; s4[j].w += pp[j].w;
      }
    }
    float bv = -INFINITY;
    int bi = 0;
#pragma unroll
    for (int j = 0; j < 8; ++j) {
      if (s4[j].x > bv) { bv = s4[j].x; bi = 4 * j; }
      if (s4[j].y > bv) { bv = s4[j].y; bi = 4 * j + 1; }
      if (s4[j].z > bv) { bv = s4[j].z; bi = 4 * j + 2; }
      if (s4[j].w > bv) { bv = s4[j].w; bi = 4 * j + 3; }
    }
    labels[(size_t)b * T + t0 + tid] = bi;
  }
}

// ---------------- Kernel 3: majority vote + S4 means + modulated output ----------------
// (R9 structure; stores non-temporal via native ext_vector type: out is
// write-once, never re-read -> keep L2 for vis/enc2 reads)
__global__ __launch_bounds__(256) void out_kernel(
    const float* __restrict__ vis, const float* __restrict__ enc2,
    const int* __restrict__ labels, float* __restrict__ out) {
  const int b = blockIdx.y;
  const int w0 = blockIdx.x * WT;
  const int tid = threadIdx.x;
  const int lane = tid & 63;
  const int wv = tid >> 6;              // wave id, wave-uniform
  __shared__ float4 S4[SROWS * (C / 4)];  // 60 KB, pre-scaled by 0.25
  __shared__ int slbl[SROWS];

  int l0 = 0, l1 = 0, l2 = 0, l3 = 0;
  if (tid < SROWS) {
    const int* lb = labels + (size_t)b * T;
    const int t = w0 + tid;
#define LCL(tt) lb[(tt) > (T - 1) ? (T - 1) : (tt)]
    l0 = LCL(t); l1 = LCL(t + 1); l2 = LCL(t + 2); l3 = LCL(t + 3);
#undef LCL
  }

  const float4* vb = (const float4*)(vis + (size_t)b * T * C);
  float4 r[18];
  {
    const int s0 = wv * (SROWS / 4);
#pragma unroll
    for (int j = 0; j < 18; ++j) {
      int t = w0 + s0 + j;
      t = t > (T - 1) ? (T - 1) : t;    // clamp; clamped rows never used
      r[j] = vb[(size_t)t * (C / 4) + lane];
    }
  }

  if (tid < SROWS) {
    const int c0 = 1 + (l0 == l1) + (l0 == l2) + (l0 == l3);
    const int c1 = 1 + (l1 == l0) + (l1 == l2) + (l1 == l3);
    const int c2 = 1 + (l2 == l0) + (l2 == l1) + (l2 == l3);
    const int c3 = 1 + (l3 == l0) + (l3 == l1) + (l3 == l2);
    int best = l0, bc = c0;
    if (c1 > bc || (c1 == bc && l1 < best)) { best = l1; bc = c1; }
    if (c2 > bc || (c2 == bc && l2 < best)) { best = l2; bc = c2; }
    if (c3 > bc || (c3 == bc && l3 < best)) { best = l3; bc = c3; }
    slbl[tid] = best;
  }

  {
    const int s0 = wv * (SROWS / 4);
#pragma unroll
    for (int s = 0; s < SROWS / 4; ++s) {
      float4 o;
      o.x = (r[s].x + r[s + 1].x + r[s + 2].x + r[s + 3].x) * 0.25f;
      o.y = (r[s].y + r[s + 1].y + r[s + 2].y + r[s + 3].y) * 0.25f;
      o.z = (r[s].z + r[s + 1].z + r[s + 2].z + r[s + 3].z) * 0.25f;
      o.w = (r[s].w + r[s + 1].w + r[s + 2].w + r[s + 3].w) * 0.25f;
      S4[(s0 + s) * (C / 4) + lane] = o;
    }
  }
  __syncthreads();

  const float4* e2b = (const float4*)(enc2 + (size_t)b * L * C);
  nfloat4* outp = (nfloat4*)out;
  const int wlim = (NW - w0) < WT ? (NW - w0) : WT;
#pragma unroll
  for (int kk = 0; kk < 2; ++kk) {
    const int k = wv + kk * 4;
#pragma unroll 4
    for (int w = 0; w < wlim; ++w) {
      const int s = w + CIC * k;
      const int lb = slbl[s];                       // LDS broadcast
      const float4 e = e2b[lb * (C / 4) + lane];    // L1/L2-hot (32 KB set)
      const float4 sv = S4[s * (C / 4) + lane];
      nfloat4 o;
      o.x = e.x * sv.x; o.y = e.y * sv.y; o.z = e.z * sv.z; o.w = e.w * sv.w;
      __builtin_nontemporal_store(
          o, &outp[(((size_t)b * NW + w0 + w) * NK + k) * (C / 4) + lane]);
    }
  }
}

extern "C" void kernel_launch(void* const* d_in, const int* in_sizes, int n_in,
                              void* d_out, int out_size, void* d_ws, size_t ws_size,
                              hipStream_t stream) {
  const float* vis   = (const float*)d_in[0];
  const float* query = (const float*)d_in[1];
  const float* W1    = (const float*)d_in[2];
  const float* b1    = (const float*)d_in[3];
  const float* W2    = (const float*)d_in[4];
  const float* b2    = (const float*)d_in[5];
  float* out = (float*)d_out;

  // Workspace: enc1 (64K f), enc2 (64K f), labels (16K int) = 576 KB
  float* enc1 = (float*)d_ws;
  float* enc2 = enc1 + (size_t)B * L * C;
  int* labels = (int*)(enc2 + (size_t)B * L * C);

  enc_kernel<<<dim3(8, B, 4), 256, 0, stream>>>(query, W1, b1, W2, b2, enc1, enc2);
  label_kernel<<<dim3(T / LT, B), 256, 0, stream>>>(vis, enc1, labels);
  out_kernel<<<dim3((NW + WT - 1) / WT, B), 256, 0, stream>>>(vis, enc2, labels, out);
}